// Round 6
// baseline (745.642 us; speedup 1.0000x reference)
//
#include <hip/hip_runtime.h>

// CausalSelfAttention: B=4, T=2048, C=1024, H=16, d_k=64
// Pipeline: convert(x,W)->bf16  |  GEMM1 qkv (+scatter Q,K,Vt)  |  flash attn  |  GEMM2 out
#define T_SEQ 2048
#define NBATCH 4
#define NHEAD 16
#define DKH 64
#define CEMB 1024

typedef unsigned short u16;
typedef __attribute__((ext_vector_type(8))) short short8;
typedef __attribute__((ext_vector_type(8))) unsigned short ushort8v;
typedef __attribute__((ext_vector_type(4))) float f32x4;

__device__ __forceinline__ u16 f2bf(float f) {
  unsigned int x = __builtin_bit_cast(unsigned int, f);
  x += 0x7FFFu + ((x >> 16) & 1u);   // RNE
  return (u16)(x >> 16);
}

__device__ __forceinline__ void async_copy16(const void* g, void* lds) {
  __builtin_amdgcn_global_load_lds(
      (const __attribute__((address_space(1))) void*)g,
      (__attribute__((address_space(3))) void*)lds, 16, 0, 0);
}

// ---------------- convert f32 -> bf16 (8 elems/thread) ----------------
__global__ __launch_bounds__(256) void k_convert(const float* __restrict__ in,
                                                 u16* __restrict__ out, int n8) {
  int i = blockIdx.x * 256 + threadIdx.x;
  if (i >= n8) return;
  const float4* p = (const float4*)in;
  float4 a = p[2 * i], b = p[2 * i + 1];
  ushort8v v;
  v[0] = f2bf(a.x); v[1] = f2bf(a.y); v[2] = f2bf(a.z); v[3] = f2bf(a.w);
  v[4] = f2bf(b.x); v[5] = f2bf(b.y); v[6] = f2bf(b.z); v[7] = f2bf(b.w);
  ((ushort8v*)out)[i] = v;
}

// ---------------- transpose+convert: W[R][C] f32 -> WT[C][R] bf16 ----------------
__global__ __launch_bounds__(256) void k_transpose(const float* __restrict__ W,
                                                   u16* __restrict__ WT, int R, int C) {
  __shared__ float tile[32][33];
  int c0 = blockIdx.x * 32, r0 = blockIdx.y * 32;
  int tx = threadIdx.x & 31;
  int ty = threadIdx.x >> 5;  // 0..7
#pragma unroll
  for (int i = 0; i < 4; ++i) {
    int r = ty + i * 8;
    tile[r][tx] = W[(size_t)(r0 + r) * C + c0 + tx];
  }
  __syncthreads();
#pragma unroll
  for (int i = 0; i < 4; ++i) {
    int cc = ty + i * 8;
    WT[(size_t)(c0 + cc) * R + r0 + tx] = f2bf(tile[tx][cc]);
  }
}

// ---------------- GEMM C = A[M,K] * BT[N,K]^T  (bf16 in, f32 acc) ----------------
// m97 structure: 128x128 tile, BK=32, 4 waves (2x2 of 64x64), 4x4 frags, global_load_lds.
// EPI=0: Cf[M,N] = acc + bias[n]   (f32 out)
// EPI=1: scatter qkv: n<1024 -> Qb[B,H,T,64]; <2048 -> Kb; else Vtb[B,H,64,T] (transposed)
template <int EPI>
__global__ __launch_bounds__(256) void k_gemm_bt(
    const u16* __restrict__ A, const u16* __restrict__ BT, const float* __restrict__ bias,
    float* __restrict__ Cf, u16* __restrict__ Qb, u16* __restrict__ Kb, u16* __restrict__ Vtb,
    int M, int N, int K) {
  __shared__ u16 As[128 * 32];
  __shared__ u16 Bs[128 * 32];
  const int tid = threadIdx.x;
  const int w = tid >> 6, l = tid & 63;
  const int g = l >> 4, lr = l & 15;
  const int m0 = blockIdx.y * 128, n0 = blockIdx.x * 128;
  const int wr = (w >> 1) * 64, wc = (w & 1) * 64;
  f32x4 acc[4][4] = {};

  const int srow = l >> 2;           // 0..15
  const int scol = (l & 3) << 3;     // 0,8,16,24
  const u16* Ag = A + (size_t)m0 * K + scol;
  const u16* Bg = BT + (size_t)n0 * K + scol;

  for (int k0 = 0; k0 < K; k0 += 32) {
#pragma unroll
    for (int i = 0; i < 2; ++i) {
      int blk = i * 4 + w;           // 0..7: 16-row chunk of the tile
      int row = blk * 16 + srow;
      async_copy16(Ag + (size_t)row * K + k0, &As[blk * 512]);
      async_copy16(Bg + (size_t)row * K + k0, &Bs[blk * 512]);
    }
    __syncthreads();
    short8 af[4], bf[4];
#pragma unroll
    for (int mi = 0; mi < 4; ++mi)
      af[mi] = *(const short8*)&As[(wr + mi * 16 + lr) * 32 + g * 8];
#pragma unroll
    for (int ni = 0; ni < 4; ++ni)
      bf[ni] = *(const short8*)&Bs[(wc + ni * 16 + lr) * 32 + g * 8];
#pragma unroll
    for (int mi = 0; mi < 4; ++mi)
#pragma unroll
      for (int ni = 0; ni < 4; ++ni)
        acc[mi][ni] = __builtin_amdgcn_mfma_f32_16x16x32_bf16(af[mi], bf[ni], acc[mi][ni], 0, 0, 0);
    __syncthreads();
  }

  if constexpr (EPI == 0) {
#pragma unroll
    for (int mi = 0; mi < 4; ++mi) {
#pragma unroll
      for (int ni = 0; ni < 4; ++ni) {
        int ng = n0 + wc + ni * 16 + lr;
        float bs = bias[ng];
#pragma unroll
        for (int r = 0; r < 4; ++r) {
          int mg = m0 + wr + mi * 16 + g * 4 + r;
          Cf[(size_t)mg * N + ng] = acc[mi][ni][r] + bs;
        }
      }
    }
  } else {
#pragma unroll
    for (int mi = 0; mi < 4; ++mi) {
      int mg0 = m0 + wr + mi * 16 + g * 4;    // t multiple of 4
      int b = mg0 >> 11;                      // /T_SEQ
      int t = mg0 & (T_SEQ - 1);
#pragma unroll
      for (int ni = 0; ni < 4; ++ni) {
        int ng = n0 + wc + ni * 16 + lr;
        float bs = bias[ng];
        int sect = ng >> 10;                  // 0=Q 1=K 2=V (uniform per frag)
        int nm = ng & 1023;
        int h = nm >> 6, d = nm & 63;
        u16 bv[4];
#pragma unroll
        for (int r = 0; r < 4; ++r) bv[r] = f2bf(acc[mi][ni][r] + bs);
        size_t hb = (size_t)b * NHEAD + h;
        if (sect == 0) {
          u16* q = Qb + (hb * T_SEQ + t) * DKH + d;
#pragma unroll
          for (int r = 0; r < 4; ++r) q[(size_t)r * DKH] = bv[r];
        } else if (sect == 1) {
          u16* kk = Kb + (hb * T_SEQ + t) * DKH + d;
#pragma unroll
          for (int r = 0; r < 4; ++r) kk[(size_t)r * DKH] = bv[r];
        } else {
          u16* vp = Vtb + (hb * DKH + d) * T_SEQ + t;  // 8B-aligned (t%4==0)
          ushort4 v4;
          v4.x = bv[0]; v4.y = bv[1]; v4.z = bv[2]; v4.w = bv[3];
          *(ushort4*)vp = v4;
        }
      }
    }
  }
}

// ---------------- flash attention (causal), 64-row paired q-tiles, 4 blocks/CU ----------------
// Each block: 4 waves x 16 q-rows = 64-row tiles, pair {j, 31-j} -> uniform 33
// kv-tile-computes. Grid 16x64 = 1024 blocks = 4/CU (LDS exactly 40KB, launch_bounds(256,4)).
// K/V staging + kf/vf reads shared by both tiles. Double-buffered staging, one
// __syncthreads per kv tile (fence required — raw s_barrier raced, R3).
// K/V content XOR-swizzle ((row&7)<<4) pre-applied on global source. P buffer per-wave
// [16][64] u16, XOR-swizzled the same way (replaces stride-72 pad; halves LDS).
// Softmax: defer-max (threshold 64 raw = 8 scaled); per-lane partials reduced at epilogue.
__global__ __launch_bounds__(256, 4) void k_attn(const u16* __restrict__ Qb,
                                                 const u16* __restrict__ Kb,
                                                 const u16* __restrict__ Vtb,
                                                 u16* __restrict__ Ob) {
  __shared__ u16 Ks[2][64 * 64];
  __shared__ u16 Vs[2][64 * 64];
  __shared__ u16 Ps[4 * 16 * 64];   // per-wave [16][64], XOR-swizzled rows
  const int tid = threadIdx.x;
  const int w = tid >> 6, l = tid & 63;
  const int g = l >> 4, lr = l & 15;
  const int bh = blockIdx.y;
  const int b = bh >> 4, h = bh & 15;
  const int jA = blockIdx.x;        // 0..15, light tile
  const int jB = 31 - jA;           // heavy tile
  const int q0a = jA * 64 + w * 16;
  const int q0b = jB * 64 + w * 16;
  const u16* Qg = Qb + (size_t)bh * T_SEQ * DKH;
  const u16* Kg = Kb + (size_t)bh * T_SEQ * DKH;
  const u16* Vg = Vtb + (size_t)bh * DKH * T_SEQ;
  u16* PsW = &Ps[w * 1024];

  // per-lane swizzled staging source bases (hoisted)
  const u16* KgL[2];
  const u16* VgL[2];
  int blkArr[2];
#pragma unroll
  for (int i = 0; i < 2; ++i) {
    int blk = i * 4 + w;
    blkArr[i] = blk;
    int x = blk * 1024 + l * 16;            // LDS byte this lane fills
    int c = x ^ (((x >> 7) & 7) << 4);      // canonical byte it must contain
    int crow = c >> 7;
    int ccolb = c & 127;
    KgL[i] = Kg + crow * DKH + (ccolb >> 1);
    VgL[i] = Vg + (size_t)crow * T_SEQ + (ccolb >> 1);
  }

  auto STAGE = [&](int bufi, int kv0) {
#pragma unroll
    for (int i = 0; i < 2; ++i) {
      async_copy16(KgL[i] + (size_t)kv0 * DKH, &Ks[bufi][blkArr[i] * 512]);
      async_copy16(VgL[i] + kv0, &Vs[bufi][blkArr[i] * 512]);
    }
  };

  STAGE(0, 0);

  // Q fragments for both q-tiles (16 rows each), held in registers
  short8 qfrA[2], qfrB[2];
#pragma unroll
  for (int ka = 0; ka < 2; ++ka) {
    qfrA[ka] = *(const short8*)&Qg[(size_t)(q0a + lr) * DKH + ka * 32 + g * 8];
    qfrB[ka] = *(const short8*)&Qg[(size_t)(q0b + lr) * DKH + ka * 32 + g * 8];
  }

  f32x4 oA[4] = {}, oB[4] = {};
  float mA[4], lpA[4], mB[4], lpB[4];
#pragma unroll
  for (int r = 0; r < 4; ++r) {
    mA[r] = -1e30f; lpA[r] = 0.f;
    mB[r] = -1e30f; lpB[r] = 0.f;
  }

  __syncthreads();

  short8 kf[4][2], vf[4][2];
  auto tile_compute = [&](int q0w_, short8 (&qfr_)[2], f32x4 (&o_)[4],
                          float (&m__)[4], float (&lp_)[4], int kv0) {
    const bool diag = (kv0 + 63 > q0w_);
    // ---- S = Q K^T (raw) ----
    f32x4 s[4] = {};
    __builtin_amdgcn_s_setprio(1);
#pragma unroll
    for (int kv = 0; kv < 4; ++kv)
#pragma unroll
      for (int ka = 0; ka < 2; ++ka)
        s[kv] = __builtin_amdgcn_mfma_f32_16x16x32_bf16(qfr_[ka], kf[kv][ka], s[kv], 0, 0, 0);
    __builtin_amdgcn_s_setprio(0);

    if (diag) {
#pragma unroll
      for (int kv = 0; kv < 4; ++kv)
#pragma unroll
        for (int r = 0; r < 4; ++r) {
          int qq = q0w_ + g * 4 + r;
          int kk = kv0 + kv * 16 + lr;
          if (kk > qq) s[kv][r] = -1e30f;
        }
    }

    // defer-max: skip cross-lane max + rescale unless local max grows past m+64 (raw)
    float pmx[4];
    bool grow = false;
#pragma unroll
    for (int r = 0; r < 4; ++r) {
      float v = fmaxf(fmaxf(s[0][r], s[1][r]), fmaxf(s[2][r], s[3][r]));
      pmx[r] = v;
      grow = grow || (v > m__[r] + 64.f);
    }
    if (__any(grow)) {
#pragma unroll
      for (int r = 0; r < 4; ++r) {
        float v = pmx[r];
        v = fmaxf(v, __shfl_xor(v, 1));
        v = fmaxf(v, __shfl_xor(v, 2));
        v = fmaxf(v, __shfl_xor(v, 4));
        v = fmaxf(v, __shfl_xor(v, 8));
        float mn = fmaxf(m__[r], v);
        float al = __expf((m__[r] - mn) * 0.125f);
        m__[r] = mn;
        lp_[r] *= al;
#pragma unroll
        for (int df = 0; df < 4; ++df) o_[df][r] *= al;
      }
    }

    // P = exp((s-m)*scale): bf16 writes into swizzled per-wave P tile + per-lane partials
#pragma unroll
    for (int r = 0; r < 4; ++r) {
      float mm = m__[r];
      float p0 = __expf((s[0][r] - mm) * 0.125f);
      float p1 = __expf((s[1][r] - mm) * 0.125f);
      float p2 = __expf((s[2][r] - mm) * 0.125f);
      float p3 = __expf((s[3][r] - mm) * 0.125f);
      lp_[r] += (p0 + p1) + (p2 + p3);
      int row4 = g * 4 + r;
      char* rowp = (char*)PsW + row4 * 128;
      int mk = (row4 & 7) << 4;
      *(u16*)(rowp + ((0 * 32 + lr * 2) ^ mk)) = f2bf(p0);
      *(u16*)(rowp + ((1 * 32 + lr * 2) ^ mk)) = f2bf(p1);
      *(u16*)(rowp + ((2 * 32 + lr * 2) ^ mk)) = f2bf(p2);
      *(u16*)(rowp + ((3 * 32 + lr * 2) ^ mk)) = f2bf(p3);
    }

    // O += P V (same-wave LDS write->read is in-order; per-wave P stripe)
    short8 pf[2];
    const int mkr = (lr & 7) << 4;
#pragma unroll
    for (int ka = 0; ka < 2; ++ka)
      pf[ka] = *(const short8*)((char*)PsW + ((lr * 128 + ka * 64 + g * 16) ^ mkr));
    __builtin_amdgcn_s_setprio(1);
#pragma unroll
    for (int df = 0; df < 4; ++df)
#pragma unroll
      for (int ka = 0; ka < 2; ++ka)
        o_[df] = __builtin_amdgcn_mfma_f32_16x16x32_bf16(pf[ka], vf[df][ka], o_[df], 0, 0, 0);
    __builtin_amdgcn_s_setprio(0);
  };

  const int ntile = jB + 1;
  for (int kt = 0; kt < ntile; ++kt) {
    const int cur = kt & 1;
    const int kv0 = kt * 64;
    if (kt + 1 < ntile) STAGE(cur ^ 1, kv0 + 64);  // prefetch next kv tile

    const char* KsB = (const char*)Ks[cur];
    const char* VsB = (const char*)Vs[cur];
#pragma unroll
    for (int kv = 0; kv < 4; ++kv)
#pragma unroll
      for (int ka = 0; ka < 2; ++ka) {
        int row = kv * 16 + lr;
        int cidx = row * 128 + ka * 64 + g * 16;
        int x = cidx ^ ((row & 7) << 4);
        kf[kv][ka] = *(const short8*)(KsB + x);
        vf[kv][ka] = *(const short8*)(VsB + x);
      }
    if (kt <= jA) tile_compute(q0a, qfrA, oA, mA, lpA, kv0);  // wave-uniform predicate
    tile_compute(q0b, qfrB, oB, mB, lpB, kv0);                // B active for all kt

    __syncthreads();  // fence; prefetch had the whole compute phase to land
  }

  // ---- epilogue: reduce per-lane partials, write Ob[B,T,C] bf16 (both q-tiles) ----
#pragma unroll
  for (int r = 0; r < 4; ++r) {
    float va = lpA[r];
    va += __shfl_xor(va, 1); va += __shfl_xor(va, 2);
    va += __shfl_xor(va, 4); va += __shfl_xor(va, 8);
    float inva = 1.0f / va;
    int tqa = q0a + g * 4 + r;
    size_t basea = ((size_t)b * T_SEQ + tqa) * CEMB + h * 64;
#pragma unroll
    for (int df = 0; df < 4; ++df)
      Ob[basea + df * 16 + lr] = f2bf(oA[df][r] * inva);

    float vb = lpB[r];
    vb += __shfl_xor(vb, 1); vb += __shfl_xor(vb, 2);
    vb += __shfl_xor(vb, 4); vb += __shfl_xor(vb, 8);
    float invb = 1.0f / vb;
    int tqb = q0b + g * 4 + r;
    size_t baseb = ((size_t)b * T_SEQ + tqb) * CEMB + h * 64;
#pragma unroll
    for (int df = 0; df < 4; ++df)
      Ob[baseb + df * 16 + lr] = f2bf(oB[df][r] * invb);
  }
}

// ---------------- launcher ----------------
extern "C" void kernel_launch(void* const* d_in, const int* in_sizes, int n_in,
                              void* d_out, int out_size, void* d_ws, size_t ws_size,
                              hipStream_t stream) {
  const float* x = (const float*)d_in[0];
  const float* Wqkv = (const float*)d_in[1];
  const float* bqkv = (const float*)d_in[2];
  const float* Wout = (const float*)d_in[3];
  const float* bout = (const float*)d_in[4];
  float* out = (float*)d_out;

  char* ws = (char*)d_ws;
  // workspace carve (total ~92.3 MB)
  u16* xb  = (u16*)(ws + 0);           // 16 MB  x bf16 [8192,1024]
  u16* WqT = (u16*)(ws + 16777216);    // 6 MB   Wqkv^T bf16 [3072,1024]
  u16* WoT = (u16*)(ws + 23068672);    // 2 MB   Wout^T bf16 [1024,1024]
  u16* Qb  = (u16*)(ws + 25165824);    // 16 MB  [B,H,T,64]
  u16* Kb  = (u16*)(ws + 41943040);    // 16 MB  [B,H,T,64]
  u16* Vtb = (u16*)(ws + 58720256);    // 16 MB  [B,H,64,T]
  u16* Ob  = (u16*)(ws + 75497472);    // 16 MB  [B,T,C] bf16

  k_convert<<<4096, 256, 0, stream>>>(x, xb, (NBATCH * T_SEQ * CEMB) / 8);
  k_transpose<<<dim3(96, 32), 256, 0, stream>>>(Wqkv, WqT, 1024, 3072);
  k_transpose<<<dim3(32, 32), 256, 0, stream>>>(Wout, WoT, 1024, 1024);
  k_gemm_bt<1><<<dim3(24, 64), 256, 0, stream>>>(xb, WqT, bqkv, nullptr, Qb, Kb, Vtb,
                                                 NBATCH * T_SEQ, 3 * CEMB, CEMB);
  k_attn<<<dim3(16, 64), 256, 0, stream>>>(Qb, Kb, Vtb, Ob);
  k_gemm_bt<0><<<dim3(8, 64), 256, 0, stream>>>(Ob, WoT, bout, out, nullptr, nullptr, nullptr,
                                                NBATCH * T_SEQ, CEMB, CEMB);
}

// Round 8
// 565.444 us; speedup vs baseline: 1.3187x; 1.3187x over previous
//
#include <hip/hip_runtime.h>

// CausalSelfAttention: B=4, T=2048, C=1024, H=16, d_k=64
// Pipeline: convert(x,W)->bf16  |  GEMM1 qkv (+scatter Q,K,Vt)  |  flash attn  |  GEMM2 out
#define T_SEQ 2048
#define NBATCH 4
#define NHEAD 16
#define DKH 64
#define CEMB 1024

typedef unsigned short u16;
typedef __attribute__((ext_vector_type(8))) short short8;
typedef __attribute__((ext_vector_type(8))) unsigned short ushort8v;
typedef __attribute__((ext_vector_type(4))) float f32x4;

__device__ __forceinline__ u16 f2bf(float f) {
  unsigned int x = __builtin_bit_cast(unsigned int, f);
  x += 0x7FFFu + ((x >> 16) & 1u);   // RNE
  return (u16)(x >> 16);
}

__device__ __forceinline__ void async_copy16(const void* g, void* lds) {
  __builtin_amdgcn_global_load_lds(
      (const __attribute__((address_space(1))) void*)g,
      (__attribute__((address_space(3))) void*)lds, 16, 0, 0);
}

// ---------------- convert f32 -> bf16 (8 elems/thread) ----------------
__global__ __launch_bounds__(256) void k_convert(const float* __restrict__ in,
                                                 u16* __restrict__ out, int n8) {
  int i = blockIdx.x * 256 + threadIdx.x;
  if (i >= n8) return;
  const float4* p = (const float4*)in;
  float4 a = p[2 * i], b = p[2 * i + 1];
  ushort8v v;
  v[0] = f2bf(a.x); v[1] = f2bf(a.y); v[2] = f2bf(a.z); v[3] = f2bf(a.w);
  v[4] = f2bf(b.x); v[5] = f2bf(b.y); v[6] = f2bf(b.z); v[7] = f2bf(b.w);
  ((ushort8v*)out)[i] = v;
}

// ---------------- transpose+convert: W[R][C] f32 -> WT[C][R] bf16 ----------------
__global__ __launch_bounds__(256) void k_transpose(const float* __restrict__ W,
                                                   u16* __restrict__ WT, int R, int C) {
  __shared__ float tile[32][33];
  int c0 = blockIdx.x * 32, r0 = blockIdx.y * 32;
  int tx = threadIdx.x & 31;
  int ty = threadIdx.x >> 5;  // 0..7
#pragma unroll
  for (int i = 0; i < 4; ++i) {
    int r = ty + i * 8;
    tile[r][tx] = W[(size_t)(r0 + r) * C + c0 + tx];
  }
  __syncthreads();
#pragma unroll
  for (int i = 0; i < 4; ++i) {
    int cc = ty + i * 8;
    WT[(size_t)(c0 + cc) * R + r0 + tx] = f2bf(tile[tx][cc]);
  }
}

// ---------------- GEMM C = A[M,K] * BT[N,K]^T  (bf16 in, f32 acc) ----------------
// m97 structure: 128x128 tile, BK=32, 4 waves (2x2 of 64x64), 4x4 frags, global_load_lds.
// XCD-aware bijective swizzle (T1): each XCD gets a contiguous chunk of work-ids
// (launcher guarantees gridDim.x*gridDim.y % 8 == 0).
// EPI=0: Cf[M,N] = acc + bias[n]   (f32 out)
// EPI=1: scatter qkv: n<1024 -> Qb[B,H,T,64]; <2048 -> Kb; else Vtb[B,H,64,T] (transposed)
template <int EPI>
__global__ __launch_bounds__(256) void k_gemm_bt(
    const u16* __restrict__ A, const u16* __restrict__ BT, const float* __restrict__ bias,
    float* __restrict__ Cf, u16* __restrict__ Qb, u16* __restrict__ Kb, u16* __restrict__ Vtb,
    int M, int N, int K) {
  __shared__ u16 As[128 * 32];
  __shared__ u16 Bs[128 * 32];
  const int tid = threadIdx.x;
  const int w = tid >> 6, l = tid & 63;
  const int g = l >> 4, lr = l & 15;
  // XCD swizzle: work-id = (orig%8)*cpx + orig/8  (bijective since nwg%8==0)
  const int orig = blockIdx.y * gridDim.x + blockIdx.x;
  const int cpx = (gridDim.x * gridDim.y) >> 3;
  const int wid = (orig & 7) * cpx + (orig >> 3);
  const int m0 = (wid / gridDim.x) * 128, n0 = (wid % gridDim.x) * 128;
  const int wr = (w >> 1) * 64, wc = (w & 1) * 64;
  f32x4 acc[4][4] = {};

  const int srow = l >> 2;           // 0..15
  const int scol = (l & 3) << 3;     // 0,8,16,24
  const u16* Ag = A + (size_t)m0 * K + scol;
  const u16* Bg = BT + (size_t)n0 * K + scol;

  for (int k0 = 0; k0 < K; k0 += 32) {
#pragma unroll
    for (int i = 0; i < 2; ++i) {
      int blk = i * 4 + w;           // 0..7: 16-row chunk of the tile
      int row = blk * 16 + srow;
      async_copy16(Ag + (size_t)row * K + k0, &As[blk * 512]);
      async_copy16(Bg + (size_t)row * K + k0, &Bs[blk * 512]);
    }
    __syncthreads();
    short8 af[4], bf[4];
#pragma unroll
    for (int mi = 0; mi < 4; ++mi)
      af[mi] = *(const short8*)&As[(wr + mi * 16 + lr) * 32 + g * 8];
#pragma unroll
    for (int ni = 0; ni < 4; ++ni)
      bf[ni] = *(const short8*)&Bs[(wc + ni * 16 + lr) * 32 + g * 8];
#pragma unroll
    for (int mi = 0; mi < 4; ++mi)
#pragma unroll
      for (int ni = 0; ni < 4; ++ni)
        acc[mi][ni] = __builtin_amdgcn_mfma_f32_16x16x32_bf16(af[mi], bf[ni], acc[mi][ni], 0, 0, 0);
    __syncthreads();
  }

  if constexpr (EPI == 0) {
#pragma unroll
    for (int mi = 0; mi < 4; ++mi) {
#pragma unroll
      for (int ni = 0; ni < 4; ++ni) {
        int ng = n0 + wc + ni * 16 + lr;
        float bs = bias[ng];
#pragma unroll
        for (int r = 0; r < 4; ++r) {
          int mg = m0 + wr + mi * 16 + g * 4 + r;
          Cf[(size_t)mg * N + ng] = acc[mi][ni][r] + bs;
        }
      }
    }
  } else {
#pragma unroll
    for (int mi = 0; mi < 4; ++mi) {
      int mg0 = m0 + wr + mi * 16 + g * 4;    // t multiple of 4
      int b = mg0 >> 11;                      // /T_SEQ
      int t = mg0 & (T_SEQ - 1);
#pragma unroll
      for (int ni = 0; ni < 4; ++ni) {
        int ng = n0 + wc + ni * 16 + lr;
        float bs = bias[ng];
        int sect = ng >> 10;                  // 0=Q 1=K 2=V (uniform per frag)
        int nm = ng & 1023;
        int h = nm >> 6, d = nm & 63;
        u16 bv[4];
#pragma unroll
        for (int r = 0; r < 4; ++r) bv[r] = f2bf(acc[mi][ni][r] + bs);
        size_t hb = (size_t)b * NHEAD + h;
        if (sect == 0) {
          u16* q = Qb + (hb * T_SEQ + t) * DKH + d;
#pragma unroll
          for (int r = 0; r < 4; ++r) q[(size_t)r * DKH] = bv[r];
        } else if (sect == 1) {
          u16* kk = Kb + (hb * T_SEQ + t) * DKH + d;
#pragma unroll
          for (int r = 0; r < 4; ++r) kk[(size_t)r * DKH] = bv[r];
        } else {
          u16* vp = Vtb + (hb * DKH + d) * T_SEQ + t;  // 8B-aligned (t%4==0)
          ushort4 v4;
          v4.x = bv[0]; v4.y = bv[1]; v4.z = bv[2]; v4.w = bv[3];
          *(ushort4*)vp = v4;
        }
      }
    }
  }
}

// ---------------- flash attention (causal), 64-row paired q-tiles ----------------
// Each block: 4 waves x 16 q-rows = 64-row tiles, pair {j, 31-j} -> uniform 33
// kv-tile-computes. Grid 16x64 = 1024 blocks. launch_bounds(256,3): VGPR cap 168
// (live state ~140; (256,4)'s cap of 128 SPILLED -> 957MB scratch writes, R6).
// LDS 40KB -> LDS allows 4 blocks/CU, VGPR limits to 3 -> 12 waves/CU.
// K/V staging + kf/vf reads shared by both tiles. Double-buffered staging, one
// __syncthreads per kv tile (fence required — raw s_barrier raced, R3).
// K/V content XOR-swizzle ((row&7)<<4) pre-applied on global source. P buffer per-wave
// [16][64] u16, XOR-swizzled the same way.
// Softmax: defer-max (threshold 64 raw = 8 scaled); per-lane partials reduced at epilogue.
__global__ __launch_bounds__(256, 3) void k_attn(const u16* __restrict__ Qb,
                                                 const u16* __restrict__ Kb,
                                                 const u16* __restrict__ Vtb,
                                                 u16* __restrict__ Ob) {
  __shared__ u16 Ks[2][64 * 64];
  __shared__ u16 Vs[2][64 * 64];
  __shared__ u16 Ps[4 * 16 * 64];   // per-wave [16][64], XOR-swizzled rows
  const int tid = threadIdx.x;
  const int w = tid >> 6, l = tid & 63;
  const int g = l >> 4, lr = l & 15;
  const int bh = blockIdx.y;
  const int b = bh >> 4, h = bh & 15;
  const int jA = blockIdx.x;        // 0..15, light tile
  const int jB = 31 - jA;           // heavy tile
  const int q0a = jA * 64 + w * 16;
  const int q0b = jB * 64 + w * 16;
  const u16* Qg = Qb + (size_t)bh * T_SEQ * DKH;
  const u16* Kg = Kb + (size_t)bh * T_SEQ * DKH;
  const u16* Vg = Vtb + (size_t)bh * DKH * T_SEQ;
  u16* PsW = &Ps[w * 1024];

  // per-lane swizzled staging source bases (hoisted)
  const u16* KgL[2];
  const u16* VgL[2];
  int blkArr[2];
#pragma unroll
  for (int i = 0; i < 2; ++i) {
    int blk = i * 4 + w;
    blkArr[i] = blk;
    int x = blk * 1024 + l * 16;            // LDS byte this lane fills
    int c = x ^ (((x >> 7) & 7) << 4);      // canonical byte it must contain
    int crow = c >> 7;
    int ccolb = c & 127;
    KgL[i] = Kg + crow * DKH + (ccolb >> 1);
    VgL[i] = Vg + (size_t)crow * T_SEQ + (ccolb >> 1);
  }

  auto STAGE = [&](int bufi, int kv0) {
#pragma unroll
    for (int i = 0; i < 2; ++i) {
      async_copy16(KgL[i] + (size_t)kv0 * DKH, &Ks[bufi][blkArr[i] * 512]);
      async_copy16(VgL[i] + kv0, &Vs[bufi][blkArr[i] * 512]);
    }
  };

  STAGE(0, 0);

  // Q fragments for both q-tiles (16 rows each), held in registers
  short8 qfrA[2], qfrB[2];
#pragma unroll
  for (int ka = 0; ka < 2; ++ka) {
    qfrA[ka] = *(const short8*)&Qg[(size_t)(q0a + lr) * DKH + ka * 32 + g * 8];
    qfrB[ka] = *(const short8*)&Qg[(size_t)(q0b + lr) * DKH + ka * 32 + g * 8];
  }

  f32x4 oA[4] = {}, oB[4] = {};
  float mA[4], lpA[4], mB[4], lpB[4];
#pragma unroll
  for (int r = 0; r < 4; ++r) {
    mA[r] = -1e30f; lpA[r] = 0.f;
    mB[r] = -1e30f; lpB[r] = 0.f;
  }

  __syncthreads();

  short8 kf[4][2], vf[4][2];
  auto tile_compute = [&](int q0w_, short8 (&qfr_)[2], f32x4 (&o_)[4],
                          float (&m__)[4], float (&lp_)[4], int kv0) {
    const bool diag = (kv0 + 63 > q0w_);
    // ---- S = Q K^T (raw) ----
    f32x4 s[4] = {};
    __builtin_amdgcn_s_setprio(1);
#pragma unroll
    for (int kv = 0; kv < 4; ++kv)
#pragma unroll
      for (int ka = 0; ka < 2; ++ka)
        s[kv] = __builtin_amdgcn_mfma_f32_16x16x32_bf16(qfr_[ka], kf[kv][ka], s[kv], 0, 0, 0);
    __builtin_amdgcn_s_setprio(0);

    if (diag) {
#pragma unroll
      for (int kv = 0; kv < 4; ++kv)
#pragma unroll
        for (int r = 0; r < 4; ++r) {
          int qq = q0w_ + g * 4 + r;
          int kk = kv0 + kv * 16 + lr;
          if (kk > qq) s[kv][r] = -1e30f;
        }
    }

    // defer-max: skip cross-lane max + rescale unless local max grows past m+64 (raw)
    float pmx[4];
    bool grow = false;
#pragma unroll
    for (int r = 0; r < 4; ++r) {
      float v = fmaxf(fmaxf(s[0][r], s[1][r]), fmaxf(s[2][r], s[3][r]));
      pmx[r] = v;
      grow = grow || (v > m__[r] + 64.f);
    }
    if (__any(grow)) {
#pragma unroll
      for (int r = 0; r < 4; ++r) {
        float v = pmx[r];
        v = fmaxf(v, __shfl_xor(v, 1));
        v = fmaxf(v, __shfl_xor(v, 2));
        v = fmaxf(v, __shfl_xor(v, 4));
        v = fmaxf(v, __shfl_xor(v, 8));
        float mn = fmaxf(m__[r], v);
        float al = __expf((m__[r] - mn) * 0.125f);
        m__[r] = mn;
        lp_[r] *= al;
#pragma unroll
        for (int df = 0; df < 4; ++df) o_[df][r] *= al;
      }
    }

    // P = exp((s-m)*scale): bf16 writes into swizzled per-wave P tile + per-lane partials
#pragma unroll
    for (int r = 0; r < 4; ++r) {
      float mm = m__[r];
      float p0 = __expf((s[0][r] - mm) * 0.125f);
      float p1 = __expf((s[1][r] - mm) * 0.125f);
      float p2 = __expf((s[2][r] - mm) * 0.125f);
      float p3 = __expf((s[3][r] - mm) * 0.125f);
      lp_[r] += (p0 + p1) + (p2 + p3);
      int row4 = g * 4 + r;
      char* rowp = (char*)PsW + row4 * 128;
      int mk = (row4 & 7) << 4;
      *(u16*)(rowp + ((0 * 32 + lr * 2) ^ mk)) = f2bf(p0);
      *(u16*)(rowp + ((1 * 32 + lr * 2) ^ mk)) = f2bf(p1);
      *(u16*)(rowp + ((2 * 32 + lr * 2) ^ mk)) = f2bf(p2);
      *(u16*)(rowp + ((3 * 32 + lr * 2) ^ mk)) = f2bf(p3);
    }

    // O += P V (same-wave LDS write->read is in-order; per-wave P stripe)
    short8 pf[2];
    const int mkr = (lr & 7) << 4;
#pragma unroll
    for (int ka = 0; ka < 2; ++ka)
      pf[ka] = *(const short8*)((char*)PsW + ((lr * 128 + ka * 64 + g * 16) ^ mkr));
    __builtin_amdgcn_s_setprio(1);
#pragma unroll
    for (int df = 0; df < 4; ++df)
#pragma unroll
      for (int ka = 0; ka < 2; ++ka)
        o_[df] = __builtin_amdgcn_mfma_f32_16x16x32_bf16(pf[ka], vf[df][ka], o_[df], 0, 0, 0);
    __builtin_amdgcn_s_setprio(0);
  };

  const int ntile = jB + 1;
  for (int kt = 0; kt < ntile; ++kt) {
    const int cur = kt & 1;
    const int kv0 = kt * 64;
    if (kt + 1 < ntile) STAGE(cur ^ 1, kv0 + 64);  // prefetch next kv tile

    const char* KsB = (const char*)Ks[cur];
    const char* VsB = (const char*)Vs[cur];
#pragma unroll
    for (int kv = 0; kv < 4; ++kv)
#pragma unroll
      for (int ka = 0; ka < 2; ++ka) {
        int row = kv * 16 + lr;
        int cidx = row * 128 + ka * 64 + g * 16;
        int x = cidx ^ ((row & 7) << 4);
        kf[kv][ka] = *(const short8*)(KsB + x);
        vf[kv][ka] = *(const short8*)(VsB + x);
      }
    if (kt <= jA) tile_compute(q0a, qfrA, oA, mA, lpA, kv0);  // block-uniform predicate
    tile_compute(q0b, qfrB, oB, mB, lpB, kv0);                // B active for all kt

    __syncthreads();  // fence; prefetch had the whole compute phase to land
  }

  // ---- epilogue: reduce per-lane partials, write Ob[B,T,C] bf16 (both q-tiles) ----
#pragma unroll
  for (int r = 0; r < 4; ++r) {
    float va = lpA[r];
    va += __shfl_xor(va, 1); va += __shfl_xor(va, 2);
    va += __shfl_xor(va, 4); va += __shfl_xor(va, 8);
    float inva = 1.0f / va;
    int tqa = q0a + g * 4 + r;
    size_t basea = ((size_t)b * T_SEQ + tqa) * CEMB + h * 64;
#pragma unroll
    for (int df = 0; df < 4; ++df)
      Ob[basea + df * 16 + lr] = f2bf(oA[df][r] * inva);

    float vb = lpB[r];
    vb += __shfl_xor(vb, 1); vb += __shfl_xor(vb, 2);
    vb += __shfl_xor(vb, 4); vb += __shfl_xor(vb, 8);
    float invb = 1.0f / vb;
    int tqb = q0b + g * 4 + r;
    size_t baseb = ((size_t)b * T_SEQ + tqb) * CEMB + h * 64;
#pragma unroll
    for (int df = 0; df < 4; ++df)
      Ob[baseb + df * 16 + lr] = f2bf(oB[df][r] * invb);
  }
}

// ---------------- launcher ----------------
extern "C" void kernel_launch(void* const* d_in, const int* in_sizes, int n_in,
                              void* d_out, int out_size, void* d_ws, size_t ws_size,
                              hipStream_t stream) {
  const float* x = (const float*)d_in[0];
  const float* Wqkv = (const float*)d_in[1];
  const float* bqkv = (const float*)d_in[2];
  const float* Wout = (const float*)d_in[3];
  const float* bout = (const float*)d_in[4];
  float* out = (float*)d_out;

  char* ws = (char*)d_ws;
  // workspace carve (total ~92.3 MB)
  u16* xb  = (u16*)(ws + 0);           // 16 MB  x bf16 [8192,1024]
  u16* WqT = (u16*)(ws + 16777216);    // 6 MB   Wqkv^T bf16 [3072,1024]
  u16* WoT = (u16*)(ws + 23068672);    // 2 MB   Wout^T bf16 [1024,1024]
  u16* Qb  = (u16*)(ws + 25165824);    // 16 MB  [B,H,T,64]
  u16* Kb  = (u16*)(ws + 41943040);    // 16 MB  [B,H,T,64]
  u16* Vtb = (u16*)(ws + 58720256);    // 16 MB  [B,H,64,T]
  u16* Ob  = (u16*)(ws + 75497472);    // 16 MB  [B,T,C] bf16

  k_convert<<<4096, 256, 0, stream>>>(x, xb, (NBATCH * T_SEQ * CEMB) / 8);
  k_transpose<<<dim3(96, 32), 256, 0, stream>>>(Wqkv, WqT, 1024, 3072);
  k_transpose<<<dim3(32, 32), 256, 0, stream>>>(Wout, WoT, 1024, 1024);
  k_gemm_bt<1><<<dim3(24, 64), 256, 0, stream>>>(xb, WqT, bqkv, nullptr, Qb, Kb, Vtb,
                                                 NBATCH * T_SEQ, 3 * CEMB, CEMB);
  k_attn<<<dim3(16, 64), 256, 0, stream>>>(Qb, Kb, Vtb, Ob);
  k_gemm_bt<0><<<dim3(8, 64), 256, 0, stream>>>(Ob, WoT, bout, out, nullptr, nullptr, nullptr,
                                                NBATCH * T_SEQ, CEMB, CEMB);
}